// Round 1
// baseline (1947.207 us; speedup 1.0000x reference)
//
#include <hip/hip_runtime.h>

#define DEV_INLINE __device__ __forceinline__

// ---------------- compile-time helpers ----------------
constexpr int roundup4(int v){ return (v+3)&~3; }
constexpr int lds_stride(int win){
  int s = roundup4(win);
  if (s % 16 == 0) s += 4;   // avoid 16/32-float strides (bank pathologies on staging writes)
  return s;
}

// ---------------- prep: transposes ----------------
// A[R][C] -> AT[C][R], write-coalesced
__global__ void transp2(const float* __restrict__ A, float* __restrict__ AT, int R, int C){
  int t = blockIdx.x*256 + threadIdx.x;
  if (t >= R*C) return;
  int r = t % R, c = t / R;
  AT[t] = A[r*C + c];
}
// W[O][I][3][3] -> WT[kk][I][O]
__global__ void transp_w(const float* __restrict__ W, float* __restrict__ WT, int O, int I){
  int t = blockIdx.x*256 + threadIdx.x;
  if (t >= O*I) return;
  int o = t % O, i = t / O;
  const float* src = W + ((long)(o*I + i))*9;
  #pragma unroll
  for (int kk=0; kk<9; ++kk) WT[(kk*I + i)*O + o] = src[kk];
}

// ---------------- stage A: enc conv + topk + dec/aux + red ----------------
// grid (30, 256) = (oh, b); block 256. h0 out: NHWC [B][30][30][64]
__global__ __launch_bounds__(256) void stage_a(
    const float* __restrict__ x, const float* __restrict__ enc_w, const float* __restrict__ enc_b,
    const float* __restrict__ decT, const float* __restrict__ dec_b,
    const float* __restrict__ redT, const float* __restrict__ red_b,
    const int* __restrict__ kp, float* __restrict__ h0, float* __restrict__ auxp)
{
  __shared__ float4 encT4[27*64];          // encT[j][c], c fastest (float4 per lane)
  __shared__ float  rows[9*32];            // [c*3+r][x] input rows oh..oh+2
  __shared__ float  sval[4][64];
  __shared__ int    sidx[4][64];
  float* encT = (float*)encT4;

  const int t = threadIdx.x, oh = blockIdx.x, b = blockIdx.y;
  const int k = *kp;

  for (int e=t; e<27*256; e+=256){ int c = e/27, j = e - c*27; encT[j*256 + c] = enc_w[e]; }
  for (int e=t; e<288; e+=256){
    int c = e/96, r = (e>>5)%3, xx = e&31;
    rows[(c*3+r)*32+xx] = x[((b*3+c)*32 + (oh+r))*32 + xx];
  }
  __syncthreads();

  const int wid = t>>6, lane = t&63;
  const float4 eb = ((const float4*)enc_b)[lane];
  const float  db = (lane<27) ? dec_b[lane] : 0.f;
  const float  rb = red_b[lane];
  const float* redTl = redT + lane;
  const float* decTl = decT + lane;
  // target decomposition for this lane (lane<27): o = ci*9 + ii*3 + jj
  const int tci = lane/9, trem = lane - tci*9;
  const int tbase = (tci*3 + trem/3)*32 + (trem%3);

  float auxacc = 0.f;

  for (int ow = wid; ow < 30; ow += 4){
    // patch (uniform across wave -> LDS broadcasts)
    float p[27];
    #pragma unroll
    for (int ci=0;ci<3;++ci)
      #pragma unroll
      for (int ii=0;ii<3;++ii)
        #pragma unroll
        for (int jj=0;jj<3;++jj)
          p[ci*9+ii*3+jj] = rows[(ci*3+ii)*32 + ow + jj];

    // enc conv: lane owns channels 4*lane..4*lane+3
    float av0=eb.x, av1=eb.y, av2=eb.z, av3=eb.w;
    #pragma unroll
    for (int j=0;j<27;++j){
      float4 w = encT4[j*64 + lane];
      av0 = fmaf(w.x, p[j], av0); av1 = fmaf(w.y, p[j], av1);
      av2 = fmaf(w.z, p[j], av2); av3 = fmaf(w.w, p[j], av3);
    }
    unsigned ab0 = __float_as_uint(av0)&0x7fffffffu;
    unsigned ab1 = __float_as_uint(av1)&0x7fffffffu;
    unsigned ab2 = __float_as_uint(av2)&0x7fffffffu;
    unsigned ab3 = __float_as_uint(av3)&0x7fffffffu;

    // exact kth-largest |v| via bitwise bisection (wave-wide ballots)
    unsigned th = 0;
    for (int bit=30; bit>=0; --bit){
      unsigned cand = th | (1u<<bit);
      int cnt = __popcll(__ballot(ab0>=cand)) + __popcll(__ballot(ab1>=cand))
              + __popcll(__ballot(ab2>=cand)) + __popcll(__ballot(ab3>=cand));
      if (cnt >= k) th = cand;
    }

    // compact survivors (a >= kth, keeps ties like the reference)
    bool k0 = ab0>=th, k1 = ab1>=th, k2 = ab2>=th, k3 = ab3>=th;
    unsigned long long B0=__ballot(k0), B1=__ballot(k1), B2=__ballot(k2), B3=__ballot(k3);
    unsigned long long below = (1ull<<lane) - 1ull;
    int n0=__popcll(B0), n1=__popcll(B1), n2=__popcll(B2), n3=__popcll(B3);
    int cnt = n0+n1+n2+n3; if (cnt > 64) cnt = 64;
    int o0 = __popcll(B0&below);
    int o1 = n0 + __popcll(B1&below);
    int o2 = n0+n1 + __popcll(B2&below);
    int o3 = n0+n1+n2 + __popcll(B3&below);
    if (k0 && o0<64){ sval[wid][o0]=av0; sidx[wid][o0]=4*lane+0; }
    if (k1 && o1<64){ sval[wid][o1]=av1; sidx[wid][o1]=4*lane+1; }
    if (k2 && o2<64){ sval[wid][o2]=av2; sidx[wid][o2]=4*lane+2; }
    if (k3 && o3<64){ sval[wid][o3]=av3; sidx[wid][o3]=4*lane+3; }
    asm volatile("s_waitcnt lgkmcnt(0)" ::: "memory");
    __builtin_amdgcn_wave_barrier();

    // sparse 1x1 convs over survivors: red (64 out) + dec (27 out, fused)
    float dacc = db, racc = rb;
    for (int jj=0; jj<cnt; ++jj){
      float v = sval[wid][jj]; int ii = sidx[wid][jj];
      racc = fmaf(v, redTl[ii*64], racc);
      if (lane < 27) dacc = fmaf(v, decTl[ii*27], dacc);
    }
    if (lane < 27){
      float dv = 1.f/(1.f + __expf(-dacc));
      float tg = rows[tbase + ow];
      float df = tg - dv;
      auxacc = fmaf(df, df, auxacc);
    }
    h0[(((b*30)+oh)*30+ow)*64 + lane] = racc;
    __builtin_amdgcn_wave_barrier();
  }

  __syncthreads();
  float* red = (float*)sval;   // 256 floats, safe now
  red[t] = auxacc; __syncthreads();
  for (int off=128; off; off>>=1){ if (t<off) red[t]+=red[t+off]; __syncthreads(); }
  if (t==0) auxp[b*30 + oh] = red[0];
}

__global__ void aux_reduce(const float* __restrict__ p, float* __restrict__ outp){
  __shared__ float s[256];
  int t = threadIdx.x; float a=0.f;
  for (int i=t; i<7680; i+=256) a += p[i];
  s[t]=a; __syncthreads();
  for (int off=128; off; off>>=1){ if (t<off) s[t]+=s[t+off]; __syncthreads(); }
  if (t==0) outp[25856] = s[0] / 6220800.0f;
}

// ---------------- BN stats (two-stage, deterministic) ----------------
template<int C, int BD>
__global__ void bn_partial(const float* __restrict__ in, float* __restrict__ psum,
                           float* __restrict__ psq, int npos){
  constexpr int GPB = BD / C;
  const int t = threadIdx.x;
  const int c = t % C, g = t / C;
  float s=0.f, q=0.f;
  for (int i = blockIdx.x*GPB + g; i < npos; i += gridDim.x*GPB){
    float v = in[i*C + c];
    s += v; q = fmaf(v, v, q);
  }
  __shared__ float ls[BD], lq[BD];
  ls[t]=s; lq[t]=q; __syncthreads();
  for (int off=BD/2; off>=C; off>>=1){
    if (t<off){ ls[t]+=ls[t+off]; lq[t]+=lq[t+off]; }
    __syncthreads();
  }
  if (t<C){ psum[blockIdx.x*C+t]=ls[t]; psq[blockIdx.x*C+t]=lq[t]; }
}

template<int C>
__global__ void bn_final(const float* __restrict__ ps, const float* __restrict__ pq,
                         const float* __restrict__ g, const float* __restrict__ b2,
                         float* __restrict__ sc, float* __restrict__ sh, float inv_n, int G){
  int t = threadIdx.x;
  if (t >= C) return;
  float s=0.f, q=0.f;
  for (int i=0;i<G;++i){ s += ps[i*C+t]; q += pq[i*C+t]; }
  float m = s*inv_n;
  float v = fmaf(q, inv_n, -m*m);
  float rs = rsqrtf(v + 1e-5f);
  float scale = g[t]*rs;
  sc[t] = scale;
  sh[t] = fmaf(-m, scale, b2[t]);
}

// ---------------- generic 3x3 valid conv, NHWC, fused BN+ReLU in, optional 2x2 maxpool out ----------------
template<int CIN,int COUT,int HIN,int WIN,bool POOL,int NPOS>
DEV_INLINE void conv_compute(const float* lds, const float* __restrict__ wt,
                             const float* __restrict__ bias, float* __restrict__ out,
                             int b, int orow, int iw0, int co, bool cok)
{
  constexpr int S = lds_stride(WIN);
  constexpr int NROWS = POOL ? 4 : 3;
  constexpr int HC = HIN-2, WC = WIN-2;
  constexpr int IVL = roundup4(NPOS+2);
  float acc0[NPOS], acc1[POOL?NPOS:1];
  const float bv = bias[co];
  #pragma unroll
  for (int p=0;p<NPOS;++p) acc0[p]=bv;
  if (POOL){
    #pragma unroll
    for (int p=0;p<NPOS;++p) acc1[p]=bv;
  }
  for (int ci=0; ci<CIN; ++ci){
    #pragma unroll
    for (int r=0;r<NROWS;++r){
      float iv[IVL];
      const float4* rp = (const float4*)(lds + (r*CIN+ci)*S + iw0);
      #pragma unroll
      for (int q=0;q<IVL/4;++q){
        float4 f = rp[q];
        iv[4*q+0]=f.x; iv[4*q+1]=f.y; iv[4*q+2]=f.z; iv[4*q+3]=f.w;
      }
      #pragma unroll
      for (int kw=0;kw<3;++kw){
        if (!POOL || r < 3){
          float w = wt[((r*3+kw)*CIN+ci)*COUT + co];
          #pragma unroll
          for (int p=0;p<NPOS;++p) acc0[p] = fmaf(iv[p+kw], w, acc0[p]);
        }
        if (POOL && r >= 1){
          float w = wt[(((r-1)*3+kw)*CIN+ci)*COUT + co];
          #pragma unroll
          for (int p=0;p<NPOS;++p) acc1[p] = fmaf(iv[p+kw], w, acc1[p]);
        }
      }
    }
  }
  if (!cok) return;
  if (POOL){
    constexpr int HP=HC/2, WP=WC/2;
    #pragma unroll
    for (int q=0;q<NPOS/2;++q){
      float m = fmaxf(fmaxf(acc0[2*q],acc0[2*q+1]), fmaxf(acc1[2*q],acc1[2*q+1]));
      out[((b*HP + orow)*WP + (iw0>>1) + q)*COUT + co] = m;
    }
  } else {
    #pragma unroll
    for (int p=0;p<NPOS;++p)
      out[((b*HC + orow)*WC + iw0 + p)*COUT + co] = acc0[p];
  }
}

template<int CIN,int COUT,int HIN,int WIN,bool POOL>
__global__ __launch_bounds__(256) void conv3x3(
    const float* __restrict__ in, const float* __restrict__ wt,
    const float* __restrict__ bias, const float* __restrict__ scale,
    const float* __restrict__ shift, float* __restrict__ out)
{
  constexpr int WC = WIN-2;
  constexpr int NROWS = POOL ? 4 : 3;
  constexpr int S = lds_stride(WIN);
  __shared__ float4 lds4[(NROWS*CIN*S)/4];
  float* lds = (float*)lds4;

  const int b = blockIdx.y, orow = blockIdx.x;
  const int ih0 = POOL ? 2*orow : orow;
  const float* src = in + ((long)(b*HIN + ih0))*WIN*CIN;
  for (int e = threadIdx.x; e < NROWS*WIN*CIN; e += 256){
    int c = e % CIN; int rest = e / CIN; int iw = rest % WIN; int r = rest / WIN;
    float v = src[e];
    v = fmaxf(fmaf(v, scale[c], shift[c]), 0.f);
    lds[(r*CIN + c)*S + iw] = v;
  }
  __syncthreads();

  const int wid = threadIdx.x>>6, lane = threadIdx.x&63;
  constexpr int NCHUNK = (COUT+63)/64;
  constexpr int NSTRIP = (NCHUNK<=2 && WC>4) ? 2 : 1;
  constexpr int NPOS0  = (NSTRIP==2) ? ((WC/2+3)&~3) : WC;
  if (wid >= NCHUNK*NSTRIP) return;   // idle wave (after the only barrier)
  int chunk, strip;
  if (NSTRIP==2){ chunk = wid & 1; strip = wid >> 1; } else { chunk = wid; strip = 0; }
  const int co = chunk*64 + lane;
  const bool cok = co < COUT;
  const int coc = cok ? co : (COUT-1);
  if (strip==0){
    conv_compute<CIN,COUT,HIN,WIN,POOL,NPOS0>(lds, wt, bias, out, b, orow, 0, coc, cok);
  } else {
    if constexpr (NSTRIP==2){
      constexpr int NPOS1 = WC - NPOS0;
      conv_compute<CIN,COUT,HIN,WIN,POOL,NPOS1>(lds, wt, bias, out, b, orow, NPOS0, coc, cok);
    }
  }
}

// ---------------- final: bnc + FC + argmax ----------------
__global__ __launch_bounds__(256) void fc_kernel(
    const float* __restrict__ a5, const float* __restrict__ scale, const float* __restrict__ shift,
    const float* __restrict__ fcT, const float* __restrict__ fc_b, float* __restrict__ outp)
{
  __shared__ float f[1024];
  __shared__ float part[256];
  __shared__ float lg[128];
  const int b = blockIdx.x, t = threadIdx.x;
  for (int e=t; e<1024; e+=256){
    int c = e & 255, hw = e >> 8;            // a5 NHWC: e = (h*2+w)*256 + c
    float v = a5[b*1024 + e];
    f[c*4 + hw] = fmaf(v, scale[c], shift[c]);   // NCHW flatten: c*4 + h*2 + w
  }
  __syncthreads();
  const int o = t & 127, half = t >> 7;
  float s = 0.f;
  if (o < 100){
    const float* fp = f + half*512;
    const float* wp = fcT + half*512*100 + o;
    for (int j=0;j<512;++j) s = fmaf(fp[j], wp[j*100], s);
  }
  part[t] = s; __syncthreads();
  if (t < 128){
    float logit = part[t] + part[t+128] + ((t<100)? fc_b[t] : 0.f);
    lg[t] = (t<100)? logit : -3.0e38f;
    if (t<100) outp[b*100 + t] = logit;
  }
  __syncthreads();
  if (t==0){
    float m = lg[0]; int mi = 0;
    for (int i=1;i<100;++i){ if (lg[i] > m){ m = lg[i]; mi = i; } }
    outp[25600 + b] = (float)mi;
  }
}

// ---------------- launch ----------------
extern "C" void kernel_launch(void* const* d_in, const int* in_sizes, int n_in,
                              void* d_out, int out_size, void* d_ws, size_t ws_size,
                              hipStream_t stream)
{
  (void)in_sizes; (void)n_in; (void)out_size;
  const float* x     = (const float*)d_in[0];
  const float* enc_w = (const float*)d_in[1];
  const float* enc_b = (const float*)d_in[2];
  const float* dec_w = (const float*)d_in[3];
  const float* dec_b = (const float*)d_in[4];
  const float* red_w = (const float*)d_in[5];
  const float* red_b = (const float*)d_in[6];
  const float* bn1_g = (const float*)d_in[7];  const float* bn1_b = (const float*)d_in[8];
  const float* c1w   = (const float*)d_in[9];  const float* c1b   = (const float*)d_in[10];
  const float* bn2_g = (const float*)d_in[11]; const float* bn2_b = (const float*)d_in[12];
  const float* c2w   = (const float*)d_in[13]; const float* c2b   = (const float*)d_in[14];
  const float* bn3_g = (const float*)d_in[15]; const float* bn3_b = (const float*)d_in[16];
  const float* c3w   = (const float*)d_in[17]; const float* c3b   = (const float*)d_in[18];
  const float* bn4_g = (const float*)d_in[19]; const float* bn4_b = (const float*)d_in[20];
  const float* c4w   = (const float*)d_in[21]; const float* c4b   = (const float*)d_in[22];
  const float* bn5_g = (const float*)d_in[23]; const float* bn5_b = (const float*)d_in[24];
  const float* c5w   = (const float*)d_in[25]; const float* c5b   = (const float*)d_in[26];
  const float* bnc_g = (const float*)d_in[27]; const float* bnc_b = (const float*)d_in[28];
  const float* fc_w  = (const float*)d_in[29]; const float* fc_b  = (const float*)d_in[30];
  const int*   kp    = (const int*)d_in[31];
  float* out = (float*)d_out;
  float* ws  = (float*)d_ws;

  // ---- workspace layout (floats) ----
  constexpr size_t OFF_DECT = 0;                      // 6912  -> pad 7168
  constexpr size_t OFF_REDT = 7168;                   // 16384
  constexpr size_t OFF_FCT  = OFF_REDT + 16384;       // 102400
  constexpr size_t OFF_WT1  = OFF_FCT + 102400;       // 55296
  constexpr size_t OFF_WT2  = OFF_WT1 + 55296;        // 110592
  constexpr size_t OFF_WT3  = OFF_WT2 + 110592;       // 184320
  constexpr size_t OFF_WT4  = OFF_WT3 + 184320;       // 276480
  constexpr size_t OFF_WT5  = OFF_WT4 + 276480;       // 442368
  constexpr size_t OFF_SS1  = OFF_WT5 + 442368;       // 128
  constexpr size_t OFF_SS2  = OFF_SS1 + 128;          // 192
  constexpr size_t OFF_SS3  = OFF_SS2 + 192;          // 256
  constexpr size_t OFF_SS4  = OFF_SS3 + 256;          // 320
  constexpr size_t OFF_SS5  = OFF_SS4 + 320;          // 384
  constexpr size_t OFF_SSC  = OFF_SS5 + 384;          // 512
  constexpr size_t OFF_PSUM = OFF_SSC + 512;          // 192*256 = 49152
  constexpr size_t OFF_PSQ  = OFF_PSUM + 49152;       // 49152
  constexpr size_t OFF_AUX  = OFF_PSQ + 49152;        // 7680 -> pad 7936
  constexpr size_t OFF_A1   = OFF_AUX + 7936;         // 256*196*96  = 4816896
  constexpr size_t OFF_H0   = OFF_A1 + 4816896;       // 256*900*64  = 14745600
  constexpr size_t OFF_A2   = OFF_H0;                 // overlays dead h0: 4718592
  constexpr size_t OFF_A3   = OFF_A2 + 4718592;       // 4096000
  constexpr size_t OFF_A4   = OFF_A3 + 4096000;       // 786432
  constexpr size_t OFF_A5   = OFF_A4 + 786432;        // 262144
  constexpr size_t TOTALF   = OFF_H0 + 14745600;
  if (ws_size < TOTALF*sizeof(float)) return;

  float* decT = ws + OFF_DECT;  float* redT = ws + OFF_REDT;  float* fcT = ws + OFF_FCT;
  float* WT1 = ws + OFF_WT1; float* WT2 = ws + OFF_WT2; float* WT3 = ws + OFF_WT3;
  float* WT4 = ws + OFF_WT4; float* WT5 = ws + OFF_WT5;
  float* ss1 = ws + OFF_SS1; float* ss2 = ws + OFF_SS2; float* ss3 = ws + OFF_SS3;
  float* ss4 = ws + OFF_SS4; float* ss5 = ws + OFF_SS5; float* ssc = ws + OFF_SSC;
  float* psum = ws + OFF_PSUM; float* psq = ws + OFF_PSQ; float* auxp = ws + OFF_AUX;
  float* a1 = ws + OFF_A1; float* h0 = ws + OFF_H0;
  float* a2 = ws + OFF_A2; float* a3 = ws + OFF_A3; float* a4 = ws + OFF_A4; float* a5 = ws + OFF_A5;

  const int G = 192;

  // prep transposes
  transp2<<<(27*256+255)/256, 256, 0, stream>>>(dec_w, decT, 27, 256);
  transp2<<<(64*256+255)/256, 256, 0, stream>>>(red_w, redT, 64, 256);
  transp2<<<(100*1024+255)/256, 256, 0, stream>>>(fc_w, fcT, 100, 1024);
  transp_w<<<(96*64+255)/256,   256, 0, stream>>>(c1w, WT1, 96, 64);
  transp_w<<<(128*96+255)/256,  256, 0, stream>>>(c2w, WT2, 128, 96);
  transp_w<<<(160*128+255)/256, 256, 0, stream>>>(c3w, WT3, 160, 128);
  transp_w<<<(192*160+255)/256, 256, 0, stream>>>(c4w, WT4, 192, 160);
  transp_w<<<(256*192+255)/256, 256, 0, stream>>>(c5w, WT5, 256, 192);

  // stage A
  stage_a<<<dim3(30,256), 256, 0, stream>>>(x, enc_w, enc_b, decT, dec_b, redT, red_b, kp, h0, auxp);
  aux_reduce<<<1, 256, 0, stream>>>(auxp, out);

  // bn1 + conv1(+pool)
  bn_partial<64,256><<<G, 256, 0, stream>>>(h0, psum, psq, 230400);
  bn_final<64><<<1, 256, 0, stream>>>(psum, psq, bn1_g, bn1_b, ss1, ss1+64, 1.f/230400.f, G);
  conv3x3<64,96,30,30,true><<<dim3(14,256), 256, 0, stream>>>(h0, WT1, c1b, ss1, ss1+64, a1);

  // bn2 + conv2
  bn_partial<96,192><<<G, 192, 0, stream>>>(a1, psum, psq, 50176);
  bn_final<96><<<1, 256, 0, stream>>>(psum, psq, bn2_g, bn2_b, ss2, ss2+96, 1.f/50176.f, G);
  conv3x3<96,128,14,14,false><<<dim3(12,256), 256, 0, stream>>>(a1, WT2, c2b, ss2, ss2+96, a2);

  // bn3 + conv3
  bn_partial<128,256><<<G, 256, 0, stream>>>(a2, psum, psq, 36864);
  bn_final<128><<<1, 256, 0, stream>>>(psum, psq, bn3_g, bn3_b, ss3, ss3+128, 1.f/36864.f, G);
  conv3x3<128,160,12,12,false><<<dim3(10,256), 256, 0, stream>>>(a2, WT3, c3b, ss3, ss3+128, a3);

  // bn4 + conv4(+pool)
  bn_partial<160,320><<<G, 320, 0, stream>>>(a3, psum, psq, 25600);
  bn_final<160><<<1, 256, 0, stream>>>(psum, psq, bn4_g, bn4_b, ss4, ss4+160, 1.f/25600.f, G);
  conv3x3<160,192,10,10,true><<<dim3(4,256), 256, 0, stream>>>(a3, WT4, c4b, ss4, ss4+160, a4);

  // bn5 + conv5
  bn_partial<192,192><<<G, 192, 0, stream>>>(a4, psum, psq, 4096);
  bn_final<192><<<1, 256, 0, stream>>>(psum, psq, bn5_g, bn5_b, ss5, ss5+192, 1.f/4096.f, G);
  conv3x3<192,256,4,4,false><<<dim3(2,256), 256, 0, stream>>>(a4, WT5, c5b, ss5, ss5+192, a5);

  // bnc + fc + argmax
  bn_partial<256,256><<<G, 256, 0, stream>>>(a5, psum, psq, 1024);
  bn_final<256><<<1, 256, 0, stream>>>(psum, psq, bnc_g, bnc_b, ssc, ssc+256, 1.f/1024.f, G);
  fc_kernel<<<256, 256, 0, stream>>>(a5, ssc, ssc+256, fcT, fc_b, out);
}